// Round 5
// baseline (248.299 us; speedup 1.0000x reference)
//
#include <hip/hip_runtime.h>
#include <hip/hip_bf16.h>
#include <math.h>

// ---------------- problem constants ----------------
#define L_SEQ 4096            // H*W
#define NB    4
#define DIMC  192
#define DIN   384             // d_inner
#define DIN2  768
#define DTRANK 12
#define DSTATE 16
#define NKX   44              // dt_rank + 2*d_state
#define G_CHUNKS 128
#define T_CHUNK  32           // L_SEQ / G_CHUNKS
#define NCH  (NB*DIN*DSTATE)  // 24576 scan channels
#define NM   (NB*L_SEQ)       // 16384 (b,l) rows
#define NBIG 448              // padded rows of fused x_proj weight (32 BC + 384 dt + pad)

typedef __attribute__((ext_vector_type(8))) short short8;     // 8 bf16 = 4 VGPRs
typedef __attribute__((ext_vector_type(4))) float floatx4;

__device__ __forceinline__ float silu_f(float v) {
    return v / (1.f + __expf(-v));
}
__device__ __forceinline__ float softplus_f(float v) {
    return fmaxf(v, 0.f) + log1pf(__expf(-fabsf(v)));
}

// async global->LDS 16B per lane (wave-uniform base + lane*16 layout)
#define GLOAD_LDS16(g, l)                                                       \
    __builtin_amdgcn_global_load_lds(                                           \
        (const __attribute__((address_space(1))) unsigned int*)(uintptr_t)(g),  \
        (__attribute__((address_space(3))) unsigned int*)(unsigned int)(uintptr_t)(l), \
        16, 0, 0)

// ---------------- convert + transpose x: (b,c,l) f32 -> (b*l, c) bf16 ----------------
__launch_bounds__(256)
__global__ void k_cvt_x(const float* __restrict__ x, __hip_bfloat16* __restrict__ xb) {
    __shared__ float s[32][33];
    const int b = blockIdx.z, c0 = blockIdx.y * 32, l0 = blockIdx.x * 32;
    const int tx = threadIdx.x, ty = threadIdx.y;   // (32, 8)
    const float* xp = x + ((size_t)b * DIMC + c0) * L_SEQ + l0;
#pragma unroll
    for (int r = 0; r < 4; ++r)
        s[ty + r*8][tx] = xp[(size_t)(ty + r*8) * L_SEQ + tx];
    __syncthreads();
    __hip_bfloat16* op = xb + ((size_t)b * L_SEQ + l0) * DIMC + c0;
#pragma unroll
    for (int r = 0; r < 4; ++r) {
        const int lr = ty + r*8;
        op[(size_t)lr * DIMC + tx] = __float2bfloat16(s[tx][lr]);
    }
}

// ------- weights: W_in, W_out -> bf16; build Wbig(448x384) = [Wx[12:44]; Wdt@Wx[:12]; 0] ----
#define NWI (DIN2*DIMC)        // 147456
#define NWO (DIMC*DIN)         // 73728
#define NWBIG (NBIG*DIN)       // 172032
__launch_bounds__(256)
__global__ void k_cvt_w(const float* __restrict__ W_in, const float* __restrict__ W_out,
                        const float* __restrict__ W_x, const float* __restrict__ W_dt,
                        __hip_bfloat16* __restrict__ wbi, __hip_bfloat16* __restrict__ wbo,
                        __hip_bfloat16* __restrict__ wbig) {
    const int i = blockIdx.x * 256 + threadIdx.x;
    if (i < NWI) {
        wbi[i] = __float2bfloat16(W_in[i]);
    } else if (i < NWI + NWO) {
        const int j = i - NWI;
        wbo[j] = __float2bfloat16(W_out[j]);
    } else if (i < NWI + NWO + NWBIG) {
        const int j = i - NWI - NWO;
        const int r = j / DIN, c = j - r * DIN;
        float v;
        if (r < 32) {
            v = W_x[(size_t)(DTRANK + r) * DIN + c];        // B,C rows
        } else if (r < 32 + DIN) {
            const int d = r - 32;                           // composite dt row
            v = 0.f;
#pragma unroll
            for (int q = 0; q < DTRANK; ++q)
                v += W_dt[d * DTRANK + q] * W_x[(size_t)q * DIN + c];
        } else {
            v = 0.f;                                        // pad rows 416..447
        }
        wbig[j] = __float2bfloat16(v);
    }
}

// ---------------- bf16 NT MFMA GEMM, small-K shape ----------------
// C[m][n] = sum_k A[m][k]*B[n][k]. BM=64, BK=64 (2x32 slabs/barrier), BN in {64,128}.
// 256 thr = 4 waves in 2x2; wave tile 32 x BN/2.
// LDS: per-slab 64B-stride rows (keeps global_load_lds lane*16 contiguity AND the
// benign bank pattern of the 32-wide layout).
// OUTMODE 0: bf16 row-major ldc            (in_proj -> xzb)
// OUTMODE 1: f32 at out[b][n][l], m=b*L+l  (out_proj)
// OUTMODE 3: x_proj fused: n<32 -> xbc f32(m,32); 32<=n<416 -> dlt f32(m,384)
//            with dlt = softplus(v + 2*b_dt[n-32])
template<int BN, int OUTMODE>
__launch_bounds__(256)
__global__ void k_mfma(const __hip_bfloat16* __restrict__ A,
                       const __hip_bfloat16* __restrict__ B,
                       float* __restrict__ Cf, __hip_bfloat16* __restrict__ Cb,
                       float* __restrict__ Cf2, const float* __restrict__ bdt,
                       int K, int ldc) {
    constexpr int WN = BN / 2;     // wave n extent
    constexpr int TN = WN / 16;    // n frags per wave
    constexpr int RB = BN / 64;    // B staging rounds per slab
    __shared__ __align__(16) __hip_bfloat16 sA[2 * 64 * 32];   // 2 k-slabs, 64 rows x 32
    __shared__ __align__(16) __hip_bfloat16 sB[2 * BN * 32];

    const int tid = threadIdx.x;
    const int lane = tid & 63;
    const int wave = tid >> 6;
    const int wm = wave >> 1, wn = wave & 1;
    const int m0 = blockIdx.x * 64;
    const int n0 = blockIdx.y * BN;
    const int mlan = lane & 15;
    const int kq = (lane >> 4) * 8;
    const int arow = tid >> 2;             // 0..63
    const int acol = (tid & 3) * 8;        // bf16 col within 32-wide slab

    floatx4 acc[2][TN];
#pragma unroll
    for (int i = 0; i < 2; ++i)
#pragma unroll
        for (int j = 0; j < TN; ++j) acc[i][j] = (floatx4){0.f, 0.f, 0.f, 0.f};

    for (int k0 = 0; k0 < K; k0 += 64) {
        __syncthreads();
#pragma unroll
        for (int kk = 0; kk < 2; ++kk)
            GLOAD_LDS16(&A[(size_t)(m0 + arow) * K + k0 + kk*32 + acol],
                        &sA[kk*2048 + arow*32 + acol]);
#pragma unroll
        for (int kk = 0; kk < 2; ++kk)
#pragma unroll
            for (int r = 0; r < RB; ++r)
                GLOAD_LDS16(&B[(size_t)(n0 + r*64 + arow) * K + k0 + kk*32 + acol],
                            &sB[kk*BN*32 + (r*64 + arow)*32 + acol]);
        __syncthreads();

        short8 af[2][2], bf[2][TN];
#pragma unroll
        for (int kk = 0; kk < 2; ++kk) {
#pragma unroll
            for (int im = 0; im < 2; ++im)
                af[kk][im] = *(const short8*)&sA[kk*2048 + (wm*32 + im*16 + mlan)*32 + kq];
#pragma unroll
            for (int jn = 0; jn < TN; ++jn)
                bf[kk][jn] = *(const short8*)&sB[kk*BN*32 + (wn*WN + jn*16 + mlan)*32 + kq];
        }
#pragma unroll
        for (int kk = 0; kk < 2; ++kk)
#pragma unroll
            for (int im = 0; im < 2; ++im)
#pragma unroll
                for (int jn = 0; jn < TN; ++jn)
                    acc[im][jn] = __builtin_amdgcn_mfma_f32_16x16x32_bf16(
                        af[kk][im], bf[kk][jn], acc[im][jn], 0, 0, 0);
    }

    const int quad = lane >> 4;
#pragma unroll
    for (int im = 0; im < 2; ++im) {
#pragma unroll
        for (int jn = 0; jn < TN; ++jn) {
            const int n = n0 + wn*WN + jn*16 + mlan;
            const int mb = m0 + wm*32 + im*16 + quad*4;
#pragma unroll
            for (int r = 0; r < 4; ++r) {
                const int m = mb + r;
                const float v = acc[im][jn][r];
                if (OUTMODE == 0) {
                    Cb[(size_t)m * ldc + n] = __float2bfloat16(v);
                } else if (OUTMODE == 1) {
                    const int bb = m >> 12, ll = m & (L_SEQ - 1);
                    Cf[((size_t)bb * DIMC + n) * L_SEQ + ll] = v;
                } else {
                    if (n < 32) {
                        Cf[(size_t)m * 32 + n] = v;
                    } else if (n < 32 + DIN) {
                        const int d = n - 32;
                        Cf2[(size_t)m * DIN + d] = softplus_f(v + 2.f * bdt[d]);
                    }
                }
            }
        }
    }
}

// ---------------- depthwise causal conv4 + SiLU: xzb bf16 (stride 768) -> bf16 -----
__launch_bounds__(256)
__global__ void k_conv(const __hip_bfloat16* __restrict__ xz, const float* __restrict__ cw,
                       const float* __restrict__ cb, __hip_bfloat16* __restrict__ xcb) {
    const int idx = blockIdx.x * 256 + threadIdx.x;   // m*DIN + d
    const int d = idx % DIN;
    const int m = idx / DIN;
    const int l = m & (L_SEQ - 1);
    const float4 w4 = *(const float4*)&cw[d * 4];
    float s = cb[d];
    const float w[4] = {w4.x, w4.y, w4.z, w4.w};
#pragma unroll
    for (int k = 0; k < 4; ++k) {
        const int ll = l - 3 + k;
        if (ll >= 0) s += __bfloat162float(xz[(size_t)(m - 3 + k) * DIN2 + d]) * w[k];
    }
    xcb[idx] = __float2bfloat16(silu_f(s));
}

// ---------------- scan phase a: per-chunk partial state + chunk product -----------
// 384 threads: one thread owns channel d, all 16 state lanes in registers.
__launch_bounds__(384)
__global__ void k_scan_a(const float* __restrict__ dlt, const __hip_bfloat16* __restrict__ xcb,
                         const float* __restrict__ xbc, const float* __restrict__ A_log,
                         float* __restrict__ S, float* __restrict__ P) {
    __shared__ float sBC[T_CHUNK * 32];
    const int tid = threadIdx.x;
    const int g = blockIdx.x, b = blockIdx.y;
    const size_t row0 = (size_t)b * L_SEQ + g * T_CHUNK;
    for (int i = tid; i < T_CHUNK * 32; i += 384)
        sBC[i] = xbc[row0 * 32 + i];
    __syncthreads();
    const int d = tid;
    float A[DSTATE];
#pragma unroll
    for (int n = 0; n < DSTATE; ++n) A[n] = -__expf(A_log[d * DSTATE + n]);
    float h[DSTATE] = {};
    float dsum = 0.f;
    const float* dl = dlt + row0 * DIN + d;
    const __hip_bfloat16* ul = xcb + row0 * DIN + d;
    for (int t = 0; t < T_CHUNK; ++t) {
        const float dv = dl[(size_t)t * DIN];
        const float uv = __bfloat162float(ul[(size_t)t * DIN]);
        const float dub = dv * uv;
        dsum += dv;
#pragma unroll
        for (int n = 0; n < DSTATE; ++n) {
            const float e = __expf(dv * A[n]);
            h[n] = e * h[n] + dub * sBC[t*32 + n];
        }
    }
    float* Sp = S + (size_t)g * NCH + (size_t)(b * DIN + d) * DSTATE;
    float* Pp = P + (size_t)g * NCH + (size_t)(b * DIN + d) * DSTATE;
#pragma unroll
    for (int n = 0; n < DSTATE; n += 4) {
        *(float4*)&Sp[n] = make_float4(h[n], h[n+1], h[n+2], h[n+3]);
        *(float4*)&Pp[n] = make_float4(__expf(A[n]*dsum), __expf(A[n+1]*dsum),
                                       __expf(A[n+2]*dsum), __expf(A[n+3]*dsum));
    }
}

// ---------------- scan phase b: sequential combine; S becomes entering state ------
__launch_bounds__(256)
__global__ void k_scan_b(float* __restrict__ Sh, const float* __restrict__ P) {
    const int ch = blockIdx.x * 256 + threadIdx.x;
    float h = 0.f;
    for (int g = 0; g < G_CHUNKS; ++g) {
        const size_t i = (size_t)g * NCH + ch;
        const float s = Sh[i];
        const float p = P[i];
        Sh[i] = h;
        h = p * h + s;
    }
}

// ---------------- scan phase c: replay + y + D*u + gate -> yb bf16 ----------------
__launch_bounds__(384)
__global__ void k_scan_c(const float* __restrict__ dlt, const __hip_bfloat16* __restrict__ xcb,
                         const float* __restrict__ xbc, const float* __restrict__ A_log,
                         const float* __restrict__ Hst, const __hip_bfloat16* __restrict__ xzb,
                         const float* __restrict__ Dv, __hip_bfloat16* __restrict__ yb) {
    __shared__ float sBC[T_CHUNK * 32];
    const int tid = threadIdx.x;
    const int g = blockIdx.x, b = blockIdx.y;
    const size_t row0 = (size_t)b * L_SEQ + g * T_CHUNK;
    for (int i = tid; i < T_CHUNK * 32; i += 384)
        sBC[i] = xbc[row0 * 32 + i];
    __syncthreads();
    const int d = tid;
    float A[DSTATE];
#pragma unroll
    for (int n = 0; n < DSTATE; ++n) A[n] = -__expf(A_log[d * DSTATE + n]);
    float h[DSTATE];
    const float* Hp = Hst + (size_t)g * NCH + (size_t)(b * DIN + d) * DSTATE;
#pragma unroll
    for (int n = 0; n < DSTATE; n += 4) {
        const float4 h4 = *(const float4*)&Hp[n];
        h[n] = h4.x; h[n+1] = h4.y; h[n+2] = h4.z; h[n+3] = h4.w;
    }
    const float Dd = Dv[d];
    const float* dl = dlt + row0 * DIN + d;
    const __hip_bfloat16* ul = xcb + row0 * DIN + d;
    const __hip_bfloat16* zl = xzb + row0 * DIN2 + DIN + d;
    __hip_bfloat16* yl = yb + row0 * DIN + d;
    for (int t = 0; t < T_CHUNK; ++t) {
        const float dv = dl[(size_t)t * DIN];
        const float uv = __bfloat162float(ul[(size_t)t * DIN]);
        const float dub = dv * uv;
        float y0 = 0.f, y1 = 0.f, y2 = 0.f, y3 = 0.f;
#pragma unroll
        for (int n = 0; n < DSTATE; n += 4) {
            float e;
            e = __expf(dv * A[n  ]); h[n  ] = e * h[n  ] + dub * sBC[t*32 + n  ]; y0 += h[n  ] * sBC[t*32 + 16 + n  ];
            e = __expf(dv * A[n+1]); h[n+1] = e * h[n+1] + dub * sBC[t*32 + n+1]; y1 += h[n+1] * sBC[t*32 + 16 + n+1];
            e = __expf(dv * A[n+2]); h[n+2] = e * h[n+2] + dub * sBC[t*32 + n+2]; y2 += h[n+2] * sBC[t*32 + 16 + n+2];
            e = __expf(dv * A[n+3]); h[n+3] = e * h[n+3] + dub * sBC[t*32 + n+3]; y3 += h[n+3] * sBC[t*32 + 16 + n+3];
        }
        const float y = (y0 + y1) + (y2 + y3);
        const float zz = __bfloat162float(zl[(size_t)t * DIN2]);
        yl[(size_t)t * DIN] = __float2bfloat16((y + Dd * uv) * silu_f(zz));
    }
}

// ---------------- launcher ----------------
extern "C" void kernel_launch(void* const* d_in, const int* in_sizes, int n_in,
                              void* d_out, int out_size, void* d_ws, size_t ws_size,
                              hipStream_t stream) {
    const float* x      = (const float*)d_in[0];
    const float* W_in   = (const float*)d_in[1];
    const float* conv_w = (const float*)d_in[2];
    const float* conv_b = (const float*)d_in[3];
    const float* W_x    = (const float*)d_in[4];
    const float* W_dt   = (const float*)d_in[5];
    const float* b_dt   = (const float*)d_in[6];
    const float* A_log  = (const float*)d_in[7];
    const float* Dvec   = (const float*)d_in[8];
    const float* W_out  = (const float*)d_in[9];
    float* out = (float*)d_out;

    char* p = (char*)d_ws;
    __hip_bfloat16* xb   = (__hip_bfloat16*)p; p += (size_t)NM * DIMC * 2;
    __hip_bfloat16* wbi  = (__hip_bfloat16*)p; p += (size_t)NWI * 2;
    __hip_bfloat16* wbo  = (__hip_bfloat16*)p; p += (size_t)NWO * 2;
    __hip_bfloat16* wbig = (__hip_bfloat16*)p; p += (size_t)NWBIG * 2;
    __hip_bfloat16* xzb  = (__hip_bfloat16*)p; p += (size_t)NM * DIN2 * 2;    // 25MB
    __hip_bfloat16* xcb  = (__hip_bfloat16*)p; p += (size_t)NM * DIN * 2;     // 12.6MB
    float*          xbc  = (float*)p;          p += (size_t)NM * 32 * 4;      // 2.1MB
    float*          dlt  = (float*)p;          p += (size_t)NM * DIN * 4;     // 25MB
    __hip_bfloat16* yb   = (__hip_bfloat16*)p; p += (size_t)NM * DIN * 2;     // 12.6MB
    float*          S    = (float*)p;          p += (size_t)G_CHUNKS * NCH * 4;
    float*          P    = (float*)p;          p += (size_t)G_CHUNKS * NCH * 4;

    // 1. weight conversion + composite dt weight; input transpose+convert
    k_cvt_w<<<dim3((NWI + NWO + NWBIG + 255) / 256), 256, 0, stream>>>(
        W_in, W_out, W_x, W_dt, wbi, wbo, wbig);
    k_cvt_x<<<dim3(L_SEQ/32, DIMC/32, NB), dim3(32, 8), 0, stream>>>(x, xb);
    // 2. in_proj: xzb(m,768) bf16 = xb(m,192) @ wbi(768,192)^T
    k_mfma<128, 0><<<dim3(NM/64, DIN2/128), 256, 0, stream>>>(
        xb, wbi, nullptr, xzb, nullptr, nullptr, DIMC, DIN2);
    // 3. depthwise causal conv + silu -> xcb bf16
    k_conv<<<dim3((NM*(size_t)DIN)/256), 256, 0, stream>>>(xzb, conv_w, conv_b, xcb);
    // 4. fused x_proj + dt_proj: xbc(m,32) f32, dlt(m,384)=softplus f32
    k_mfma<64, 3><<<dim3(NM/64, NBIG/64), 256, 0, stream>>>(
        xcb, wbig, xbc, nullptr, dlt, b_dt, DIN, 0);
    // 5. chunked selective scan
    k_scan_a<<<dim3(G_CHUNKS, NB), 384, 0, stream>>>(dlt, xcb, xbc, A_log, S, P);
    k_scan_b<<<dim3(NCH/256), 256, 0, stream>>>(S, P);
    k_scan_c<<<dim3(G_CHUNKS, NB), 384, 0, stream>>>(dlt, xcb, xbc, A_log, S, xzb, Dvec, yb);
    // 6. out_proj: out(b,192,l) = yb(m,384) @ wbo(192,384)^T
    k_mfma<64, 1><<<dim3(NM/64, DIMC/64), 256, 0, stream>>>(
        yb, wbo, out, nullptr, nullptr, nullptr, DIN, 0);
}